// Round 1
// baseline (109.782 us; speedup 1.0000x reference)
//
#include <hip/hip_runtime.h>

#define HW       262144      // 512*512
#define N_ELEM   8388608     // 32 * HW
#define NBINS    10

// d_ws layout (words):
//   u32 ws[0..9]   : bin counts
//   u32 ws[10]     : valid count
//   u32 ws[11]     : pos count
//   f32 ws[16..25] : per-bin sum of log(pred)*pos            (pos sums)
//   f32 ws[26..35] : per-bin sum of log(1-pred)*neg*(1-hm)^4 (neg sums)
#define WS_WORDS 36

__global__ __launch_bounds__(256) void ghm_accum(
    const float* __restrict__ pred, const float* __restrict__ target,
    unsigned int* __restrict__ wsU, float* __restrict__ wsF)
{
    __shared__ float        s_pos[NBINS];
    __shared__ float        s_neg[NBINS];
    __shared__ unsigned int s_cnt[NBINS];
    __shared__ unsigned int s_valid;
    __shared__ unsigned int s_npos;

    const int tid = threadIdx.x;
    if (tid < NBINS) { s_pos[tid] = 0.f; s_neg[tid] = 0.f; s_cnt[tid] = 0u; }
    if (tid == 0) { s_valid = 0u; s_npos = 0u; }
    __syncthreads();

    unsigned int myValid = 0u, myPos = 0u;

    const int nvec   = N_ELEM / 4;
    const int stride = gridDim.x * blockDim.x;
    for (int v = blockIdx.x * blockDim.x + tid; v < nvec; v += stride) {
        const int e = v << 2;              // element index (multiple of 4)
        const int b = e >> 18;             // batch (HW = 2^18)
        const int r = e & (HW - 1);        // pixel within image

        const float4 p4  = *reinterpret_cast<const float4*>(pred + e);
        const float* tb  = target + (size_t)b * (3 * HW) + r;
        const float4 hm4 = *reinterpret_cast<const float4*>(tb);
        const float4 vl4 = *reinterpret_cast<const float4*>(tb + HW);
        const float4 ps4 = *reinterpret_cast<const float4*>(tb + 2 * HW);

        #pragma unroll
        for (int j = 0; j < 4; ++j) {
            const float p  = (&p4.x)[j];
            const float hm = (&hm4.x)[j];
            const float vl = (&vl4.x)[j];
            const float ps = (&ps4.x)[j];

            if (!(vl > 0.f)) continue;     // valid = target1 > 0
            myValid++;

            const float g = fabsf(p * vl - ps);
            // idx = searchsorted(edges, g, 'right') - 1, clipped to [0,9]
            const int idx = (g >= 0.1f) + (g >= 0.2f) + (g >= 0.3f) +
                            (g >= 0.4f) + (g >= 0.5f) + (g >= 0.6f) +
                            (g >= 0.7f) + (g >= 0.8f) + (g >= 0.9f);
            const bool in_bin = (g < 1.000001f);   // g >= edges[0]=0 always
            if (!in_bin) continue;                 // (never hit with these inputs)

            atomicAdd(&s_cnt[idx], 1u);

            if (ps != 0.f) {                       // positive sample
                myPos++;
                atomicAdd(&s_pos[idx], logf(p));   // * ps(=1)
            }
            const float ng = vl - ps;              // neg indicator
            if (ng != 0.f) {
                const float t  = 1.f - hm;
                const float t2 = t * t;
                atomicAdd(&s_neg[idx], logf(1.f - p) * ng * (t2 * t2));
            }
        }
    }

    atomicAdd(&s_valid, myValid);
    atomicAdd(&s_npos,  myPos);
    __syncthreads();

    if (tid < NBINS) {
        atomicAdd(&wsU[tid],      s_cnt[tid]);
        atomicAdd(&wsF[16 + tid], s_pos[tid]);
        atomicAdd(&wsF[26 + tid], s_neg[tid]);
    }
    if (tid == 0) {
        atomicAdd(&wsU[10], s_valid);
        atomicAdd(&wsU[11], s_npos);
    }
}

__global__ void ghm_final(const unsigned int* __restrict__ wsU,
                          const float* __restrict__ wsF,
                          float* __restrict__ out)
{
    if (threadIdx.x == 0 && blockIdx.x == 0) {
        float tot = (float)wsU[10];
        if (tot < 1.f) tot = 1.f;

        int nne = 0;
        for (int b = 0; b < NBINS; ++b) if (wsU[b] > 0u) nne++;
        const float nn = (nne > 0) ? (float)nne : 1.f;

        float sp = 0.f, sn = 0.f;
        for (int b = 0; b < NBINS; ++b) {
            const float c = (float)wsU[b];
            // w_per_bin = (counts>0 ? tot/max(counts,1) : 0) / n_nonempty
            const float w = (wsU[b] > 0u) ? (tot / fmaxf(c, 1.f)) / nn : 0.f;
            sp += wsF[16 + b] * w;
            sn += wsF[26 + b] * w;
        }
        const float loss = (wsU[11] == 0u) ? (-sn / tot) : (-(sp + sn) / tot);
        out[0] = loss;
    }
}

extern "C" void kernel_launch(void* const* d_in, const int* in_sizes, int n_in,
                              void* d_out, int out_size, void* d_ws, size_t ws_size,
                              hipStream_t stream)
{
    const float* pred   = (const float*)d_in[0];
    const float* target = (const float*)d_in[1];
    float*       out    = (float*)d_out;

    unsigned int* wsU = (unsigned int*)d_ws;
    float*        wsF = (float*)d_ws;

    // zero the 36-word accumulator region every call (ws is not re-poisoned)
    hipMemsetAsync(d_ws, 0, WS_WORDS * sizeof(float), stream);

    const int block  = 256;
    const int blocks = 2048;   // 256 CUs * 8; grid-stride covers 2,097,152 vec4s
    ghm_accum<<<blocks, block, 0, stream>>>(pred, target, wsU, wsF);
    ghm_final<<<1, 64, 0, stream>>>(wsU, wsF, out);
}

// Round 2
// 103.815 us; speedup vs baseline: 1.0575x; 1.0575x over previous
//
#include <hip/hip_runtime.h>

#define HW       262144      // 512*512
#define N_ELEM   8388608     // 32 * HW
#define NBINS    10
#define EDGE_HI  (1.0f + 1e-6f)

// d_ws layout: 21 fp32 accumulators, each on its own 128-B line:
//   ws[(0..9)*32]   : per-bin count
//   ws[(10..19)*32] : per-bin combined weighted-log sum
//   ws[20*32]       : valid count
#define WS_SLOTS 21
#define WS_BYTES (WS_SLOTS * 128)

__global__ __launch_bounds__(256) void ghm_accum(
    const float* __restrict__ pred, const float* __restrict__ target,
    float* __restrict__ ws)
{
    // per-lane histogram columns: sh[q][bin][lane], q=0 count, q=1 sum
    __shared__ float sh[2 * NBINS * 64];      // 5 KB
    __shared__ float sh2[20 * 8];
    __shared__ float shv[4];

    const int tid  = threadIdx.x;
    const int lane = tid & 63;

    #pragma unroll
    for (int i = tid; i < 2 * NBINS * 64; i += 256) sh[i] = 0.f;
    __syncthreads();

    float validAcc = 0.f;

    const int nvec   = N_ELEM / 4;
    const int stride = gridDim.x * blockDim.x;
    for (int v = blockIdx.x * blockDim.x + tid; v < nvec; v += stride) {
        const int e = v << 2;              // element index (multiple of 4)
        const int b = e >> 18;             // batch (HW = 2^18)
        const int r = e & (HW - 1);        // pixel within image

        const float4 p4  = *reinterpret_cast<const float4*>(pred + e);
        const float* tb  = target + (size_t)b * (3 * HW) + r;
        const float4 hm4 = *reinterpret_cast<const float4*>(tb);
        const float4 vl4 = *reinterpret_cast<const float4*>(tb + HW);
        const float4 ps4 = *reinterpret_cast<const float4*>(tb + 2 * HW);

        #pragma unroll
        for (int j = 0; j < 4; ++j) {
            const float p  = (&p4.x)[j];
            const float hm = (&hm4.x)[j];
            const float vl = (&vl4.x)[j];   // 0.0 or 1.0
            const float ps = (&ps4.x)[j];   // 0.0 or 1.0, ps <= vl

            validAcc += vl;                 // exact integer adds in fp32

            const float g = fabsf(p * vl - ps);
            // idx = searchsorted(edges, g, 'right') - 1, clipped to [0,9]
            const int idx = (g >= 0.1f) + (g >= 0.2f) + (g >= 0.3f) +
                            (g >= 0.4f) + (g >= 0.5f) + (g >= 0.6f) +
                            (g >= 0.7f) + (g >= 0.8f) + (g >= 0.9f);

            const bool inb   = (vl > 0.f) & (g < EDGE_HI);
            const bool isPos = (ps != 0.f);

            // one log per element: log(p) for pos, log(1-p) for neg
            const float x  = isPos ? p : 1.f - p;
            const float l  = __logf(x);
            const float t  = 1.f - hm;
            const float t2 = t * t;
            const float nw = t2 * t2;       // (1-hm)^4

            const float cntv = inb ? 1.f : 0.f;
            const float sumv = inb ? (isPos ? l : l * nw) : 0.f;

            // per-lane column: no intra-wave address collisions
            const int col = idx * 64 + lane;
            atomicAdd(&sh[col],             cntv);
            atomicAdd(&sh[NBINS * 64 + col], sumv);
        }
    }

    __syncthreads();

    // fold 20 rows of 64 columns: thread (r,k) sums 8 values
    {
        const int rr = tid >> 3, k = tid & 7;
        if (rr < 20) {
            const float* row = sh + rr * 64;
            float part = 0.f;
            #pragma unroll
            for (int j = 0; j < 8; ++j) part += row[k * 8 + j];
            sh2[rr * 8 + k] = part;
        }
    }

    // wave-reduce validAcc
    #pragma unroll
    for (int off = 32; off; off >>= 1) validAcc += __shfl_down(validAcc, off);
    if (lane == 0) shv[tid >> 6] = validAcc;
    __syncthreads();

    if (tid < 20) {
        const float* row = sh2 + tid * 8;
        float s = row[0] + row[1] + row[2] + row[3] +
                  row[4] + row[5] + row[6] + row[7];
        atomicAdd(&ws[tid * 32], s);
    }
    if (tid == 0) {
        atomicAdd(&ws[20 * 32], shv[0] + shv[1] + shv[2] + shv[3]);
    }
}

__global__ void ghm_final(const float* __restrict__ ws, float* __restrict__ out)
{
    if (threadIdx.x == 0 && blockIdx.x == 0) {
        float tot = ws[20 * 32];
        if (tot < 1.f) tot = 1.f;

        int nne = 0;
        for (int b = 0; b < NBINS; ++b) if (ws[b * 32] > 0.f) nne++;
        const float nn = (nne > 0) ? (float)nne : 1.f;

        float s = 0.f;
        for (int b = 0; b < NBINS; ++b) {
            const float c = ws[b * 32];
            const float w = (c > 0.f) ? (tot / fmaxf(c, 1.f)) / nn : 0.f;
            s += ws[(10 + b) * 32] * w;
        }
        out[0] = -s / tot;
    }
}

extern "C" void kernel_launch(void* const* d_in, const int* in_sizes, int n_in,
                              void* d_out, int out_size, void* d_ws, size_t ws_size,
                              hipStream_t stream)
{
    const float* pred   = (const float*)d_in[0];
    const float* target = (const float*)d_in[1];
    float*       out    = (float*)d_out;
    float*       ws     = (float*)d_ws;

    hipMemsetAsync(d_ws, 0, WS_BYTES, stream);

    ghm_accum<<<2048, 256, 0, stream>>>(pred, target, ws);
    ghm_final<<<1, 64, 0, stream>>>(ws, out);
}

// Round 3
// 102.287 us; speedup vs baseline: 1.0733x; 1.0149x over previous
//
#include <hip/hip_runtime.h>

#define HW        262144     // 512*512 elements per image plane
#define NBINS     10
#define EDGE_HI   (1.0f + 1e-6f)
#define TILE_VEC  1024       // vec4s per block tile (4 k-steps * 256 threads)

// d_ws: 21 quantities * 32 replica slots (fp32):
//   q in [0,10)  : per-bin count
//   q in [10,20) : per-bin combined weighted-log sum
//   q = 20       : valid count
#define WS_FLOATS (21 * 32)

__global__ __launch_bounds__(256) void ghm_accum(
    const float* __restrict__ pred, const float* __restrict__ target,
    float* __restrict__ ws)
{
    __shared__ float sh[2 * NBINS * 64];   // per-lane histogram columns
    __shared__ float sh2[20 * 8];
    __shared__ float shv[4];

    const int tid  = threadIdx.x;
    const int lane = tid & 63;

    #pragma unroll
    for (int i = tid; i < 2 * NBINS * 64; i += 256) sh[i] = 0.f;
    __syncthreads();

    // block -> (image, tile): 64 tiles of 1024 vec4s per image, 32 images
    const int img  = blockIdx.x >> 6;
    const int tile = blockIdx.x & 63;
    const int v0   = tile * TILE_VEC + tid;          // vec4 index in image (+k*256)

    const float* pp = pred   + (size_t)img * HW;
    const float* th = target + (size_t)img * (3 * HW);

    // ---- issue ALL 16 loads up front (16 KB in flight per wave) ----
    float4 p4[4], hm4[4], vl4[4], ps4[4];
    #pragma unroll
    for (int k = 0; k < 4; ++k) {
        const int r = (v0 + (k << 8)) << 2;          // element offset in image
        p4[k]  = *reinterpret_cast<const float4*>(pp + r);
        hm4[k] = *reinterpret_cast<const float4*>(th + r);
        vl4[k] = *reinterpret_cast<const float4*>(th + HW + r);
        ps4[k] = *reinterpret_cast<const float4*>(th + 2 * HW + r);
    }

    float validAcc = 0.f;

    #pragma unroll
    for (int k = 0; k < 4; ++k) {
        #pragma unroll
        for (int j = 0; j < 4; ++j) {
            const float p  = (&p4[k].x)[j];
            const float hm = (&hm4[k].x)[j];
            const float vl = (&vl4[k].x)[j];   // 0.0 or 1.0
            const float ps = (&ps4[k].x)[j];   // 0.0 or 1.0, ps <= vl

            validAcc += vl;

            const float g = fabsf(p * vl - ps);
            const int idx = (g >= 0.1f) + (g >= 0.2f) + (g >= 0.3f) +
                            (g >= 0.4f) + (g >= 0.5f) + (g >= 0.6f) +
                            (g >= 0.7f) + (g >= 0.8f) + (g >= 0.9f);

            const bool inb   = (vl > 0.f) & (g < EDGE_HI);
            const bool isPos = (ps != 0.f);

            const float x  = isPos ? p : 1.f - p;
            const float l  = __logf(x);
            const float t  = 1.f - hm;
            const float t2 = t * t;
            const float nw = t2 * t2;                  // (1-hm)^4

            const float fac  = inb ? (isPos ? 1.f : nw) : 0.f;
            const float cntv = inb ? 1.f : 0.f;

            const int col = idx * 64 + lane;           // conflict-free column
            atomicAdd(&sh[col],              cntv);
            atomicAdd(&sh[NBINS * 64 + col], l * fac);
        }
    }

    __syncthreads();

    // fold 20 rows of 64 columns: thread (r,k) sums 8 values
    {
        const int rr = tid >> 3, kk = tid & 7;
        if (rr < 20) {
            const float* row = sh + rr * 64;
            float part = 0.f;
            #pragma unroll
            for (int j = 0; j < 8; ++j) part += row[kk * 8 + j];
            sh2[rr * 8 + kk] = part;
        }
    }

    // wave-reduce validAcc
    #pragma unroll
    for (int off = 32; off; off >>= 1) validAcc += __shfl_down(validAcc, off);
    if (lane == 0) shv[tid >> 6] = validAcc;
    __syncthreads();

    const int slot = blockIdx.x & 31;                  // spread tail atomics
    if (tid < 20) {
        const float* row = sh2 + tid * 8;
        float s = row[0] + row[1] + row[2] + row[3] +
                  row[4] + row[5] + row[6] + row[7];
        atomicAdd(&ws[tid * 32 + slot], s);
    }
    if (tid == 0) {
        atomicAdd(&ws[20 * 32 + slot], shv[0] + shv[1] + shv[2] + shv[3]);
    }
}

__global__ void ghm_final(const float* __restrict__ ws, float* __restrict__ out)
{
    __shared__ float q[21];
    const int tid = threadIdx.x;
    if (tid < 21) {
        float s = 0.f;
        #pragma unroll
        for (int j = 0; j < 32; ++j) s += ws[tid * 32 + j];
        q[tid] = s;
    }
    __syncthreads();

    if (tid == 0) {
        float tot = q[20];
        if (tot < 1.f) tot = 1.f;

        int nne = 0;
        for (int b = 0; b < NBINS; ++b) if (q[b] > 0.f) nne++;
        const float nn = (nne > 0) ? (float)nne : 1.f;

        float s = 0.f;
        for (int b = 0; b < NBINS; ++b) {
            const float c = q[b];
            const float w = (c > 0.f) ? (tot / fmaxf(c, 1.f)) / nn : 0.f;
            s += q[10 + b] * w;
        }
        out[0] = -s / tot;
    }
}

extern "C" void kernel_launch(void* const* d_in, const int* in_sizes, int n_in,
                              void* d_out, int out_size, void* d_ws, size_t ws_size,
                              hipStream_t stream)
{
    const float* pred   = (const float*)d_in[0];
    const float* target = (const float*)d_in[1];
    float*       out    = (float*)d_out;
    float*       ws     = (float*)d_ws;

    hipMemsetAsync(d_ws, 0, WS_FLOATS * sizeof(float), stream);

    ghm_accum<<<2048, 256, 0, stream>>>(pred, target, ws);
    ghm_final<<<1, 64, 0, stream>>>(ws, out);
}

// Round 4
// 42.222 us; speedup vs baseline: 2.6001x; 2.4226x over previous
//
#include <hip/hip_runtime.h>

#define HW       262144      // 512*512 elements per image plane
#define NBINS    10
#define EDGE_HI  (1.0f + 1e-6f)

// d_ws: 21 cumulative quantities * 32 replica slots (fp32):
//   q in [0,10)  : C[k] = count of (valid & in-bin & g >= k/10)
//   q in [10,20) : S[k] = sum of weighted-log where g >= k/10
//   q = 20       : valid count
#define WS_FLOATS (21 * 32)

__global__ __launch_bounds__(256) void ghm_accum(
    const float* __restrict__ pred, const float* __restrict__ target,
    float* __restrict__ ws)
{
    __shared__ float shred[4][32];     // per-wave partials (row-padded)

    const int tid  = threadIdx.x;
    const int lane = tid & 63;
    const int wv   = tid >> 6;

    // 1024 blocks: 32 blocks per image, each block owns 2048 consecutive vec4s
    const int img      = blockIdx.x >> 5;
    const int tileBase = (blockIdx.x & 31) * 2048;

    const float* pp = pred   + (size_t)img * HW;
    const float* th = target + (size_t)img * (3 * HW);

    float ck[NBINS], sk[NBINS];
    #pragma unroll
    for (int b = 0; b < NBINS; ++b) { ck[b] = 0.f; sk[b] = 0.f; }
    float validAcc = 0.f;

    #pragma unroll 1
    for (int c = 0; c < 2; ++c) {
        const int v0 = tileBase + c * 1024 + tid;

        float4 p4[4], hm4[4], vl4[4], ps4[4];
        #pragma unroll
        for (int k = 0; k < 4; ++k) {
            const int r = (v0 + (k << 8)) << 2;
            p4[k]  = *reinterpret_cast<const float4*>(pp + r);
            hm4[k] = *reinterpret_cast<const float4*>(th + r);
            vl4[k] = *reinterpret_cast<const float4*>(th + HW + r);
            ps4[k] = *reinterpret_cast<const float4*>(th + 2 * HW + r);
        }

        #pragma unroll
        for (int k = 0; k < 4; ++k) {
            #pragma unroll
            for (int j = 0; j < 4; ++j) {
                const float p  = (&p4[k].x)[j];
                const float hm = (&hm4[k].x)[j];
                const float vl = (&vl4[k].x)[j];   // 0.0 or 1.0
                const float ps = (&ps4[k].x)[j];   // 0.0 or 1.0, ps <= vl

                validAcc += vl;

                const float g   = fabsf(__builtin_fmaf(p, vl, -ps));
                const bool inb  = (vl > 0.f) & (g < EDGE_HI);
                const bool isP  = (ps != 0.f);

                const float x  = isP ? p : 1.f - p;
                const float l  = __logf(x);
                const float t  = 1.f - hm;
                const float t2 = t * t;
                const float nw = t2 * t2;              // (1-hm)^4

                const float cb   = inb ? 1.f : 0.f;
                const float lfac = inb ? (isP ? l : l * nw) : 0.f;

                ck[0] += cb;
                sk[0] += lfac;
                #pragma unroll
                for (int b = 1; b < NBINS; ++b) {
                    // compile-time edge literal
                    const float edge = (b == 1) ? 0.1f : (b == 2) ? 0.2f :
                                       (b == 3) ? 0.3f : (b == 4) ? 0.4f :
                                       (b == 5) ? 0.5f : (b == 6) ? 0.6f :
                                       (b == 7) ? 0.7f : (b == 8) ? 0.8f : 0.9f;
                    const float sel = (g >= edge) ? 1.f : 0.f;
                    ck[b] = __builtin_fmaf(sel, cb,   ck[b]);
                    sk[b] = __builtin_fmaf(sel, lfac, sk[b]);
                }
            }
        }
    }

    // 64-lane butterfly reduce of the 21 register accumulators
    #pragma unroll
    for (int off = 32; off; off >>= 1) {
        #pragma unroll
        for (int b = 0; b < NBINS; ++b) {
            ck[b] += __shfl_xor(ck[b], off);
            sk[b] += __shfl_xor(sk[b], off);
        }
        validAcc += __shfl_xor(validAcc, off);
    }

    if (lane == 0) {
        #pragma unroll
        for (int b = 0; b < NBINS; ++b) {
            shred[wv][b]      = ck[b];
            shred[wv][10 + b] = sk[b];
        }
        shred[wv][20] = validAcc;
    }
    __syncthreads();

    if (tid < 21) {
        const float s = shred[0][tid] + shred[1][tid] +
                        shred[2][tid] + shred[3][tid];
        atomicAdd(&ws[tid * 32 + (blockIdx.x & 31)], s);
    }
}

__global__ void ghm_final(const float* __restrict__ ws, float* __restrict__ out)
{
    __shared__ float q[21];
    const int tid = threadIdx.x;
    if (tid < 21) {
        float s = 0.f;
        #pragma unroll
        for (int j = 0; j < 32; ++j) s += ws[tid * 32 + j];
        q[tid] = s;
    }
    __syncthreads();

    if (tid == 0) {
        float tot = q[20];
        if (tot < 1.f) tot = 1.f;

        // cumulative -> per-bin (counts are exact integers < 2^24)
        float cnt[NBINS], sv[NBINS];
        for (int b = 0; b < NBINS - 1; ++b) {
            cnt[b] = q[b]      - q[b + 1];
            sv[b]  = q[10 + b] - q[11 + b];
        }
        cnt[NBINS - 1] = q[NBINS - 1];
        sv[NBINS - 1]  = q[19];

        int nne = 0;
        for (int b = 0; b < NBINS; ++b) if (cnt[b] > 0.f) nne++;
        const float nn = (nne > 0) ? (float)nne : 1.f;

        float s = 0.f;
        for (int b = 0; b < NBINS; ++b) {
            const float w = (cnt[b] > 0.f) ? (tot / fmaxf(cnt[b], 1.f)) / nn : 0.f;
            s += sv[b] * w;
        }
        out[0] = -s / tot;
    }
}

extern "C" void kernel_launch(void* const* d_in, const int* in_sizes, int n_in,
                              void* d_out, int out_size, void* d_ws, size_t ws_size,
                              hipStream_t stream)
{
    const float* pred   = (const float*)d_in[0];
    const float* target = (const float*)d_in[1];
    float*       out    = (float*)d_out;
    float*       ws     = (float*)d_ws;

    hipMemsetAsync(d_ws, 0, WS_FLOATS * sizeof(float), stream);

    ghm_accum<<<1024, 256, 0, stream>>>(pred, target, ws);
    ghm_final<<<1, 64, 0, stream>>>(ws, out);
}